// Round 7
// baseline (12062.555 us; speedup 1.0000x reference)
//
#include <hip/hip_runtime.h>
#include <cstdint>
#include <cstddef>

#define N_NODES_C 100000
#define N_EDGES_C 1250000
#define N_PAIRS_C 200000
#define IN_DIM_C 128
#define HID_C 64

// graph-build geometry
#define NB_S 256
#define BSH 9
#define NPB 512
#define NBKT 196
#define SEG_CAP 8192

// W LDS row stride (padded +4 words: breaks staging-write bank conflicts)
#define WST 68

// ---------------- scan helpers ----------------

#define SCAN_TPB 256
#define SCAN_IPT 4
#define SCAN_ELEMS 1024

__global__ void k_scan_partial(const int* __restrict__ in, int* __restrict__ outp,
                               int* __restrict__ blocksums, int n) {
    __shared__ int sd[SCAN_TPB];
    int tid = threadIdx.x;
    int base = blockIdx.x * SCAN_ELEMS + tid * SCAN_IPT;
    int v[SCAN_IPT]; int s = 0;
    for (int k = 0; k < SCAN_IPT; k++) { int idx = base + k; v[k] = (idx < n) ? in[idx] : 0; s += v[k]; }
    sd[tid] = s;
    __syncthreads();
    for (int off = 1; off < SCAN_TPB; off <<= 1) {
        int t = (tid >= off) ? sd[tid - off] : 0;
        __syncthreads();
        sd[tid] += t;
        __syncthreads();
    }
    int excl = sd[tid] - s;
    for (int k = 0; k < SCAN_IPT; k++) { int idx = base + k; if (idx < n) outp[idx] = excl; excl += v[k]; }
    if (tid == SCAN_TPB - 1) blocksums[blockIdx.x] = sd[tid];
}

__global__ void k_scan_blocks(int* __restrict__ bs, int nb) {
    __shared__ int sd[128];
    int t = threadIdx.x;
    int v = (t < nb) ? bs[t] : 0;
    sd[t] = v;
    __syncthreads();
    for (int off = 1; off < 128; off <<= 1) {
        int u = (t >= off) ? sd[t - off] : 0;
        __syncthreads();
        sd[t] += u;
        __syncthreads();
    }
    if (t < nb) bs[t] = sd[t] - v;
}

__global__ void k_scan_addg(int* __restrict__ arr, const int* __restrict__ bs, int n) {
    int i = blockIdx.x * blockDim.x + threadIdx.x;
    if (i < n) arr[i] += bs[i >> 10];
}

// ---------------- graph build: two-level counting sort ----------------

__global__ __launch_bounds__(256) void k_hist(const int* __restrict__ dst,
                                              int* __restrict__ histT, int e) {
    __shared__ int lh[NBKT];
    int tid = threadIdx.x, k = blockIdx.x;
    if (tid < NBKT) lh[tid] = 0;
    __syncthreads();
    int chunk = (e + NB_S - 1) / NB_S;
    int i0 = k * chunk, i1 = min(i0 + chunk, e);
    for (int i = i0 + tid; i < i1; i += 256) atomicAdd(&lh[dst[i] >> BSH], 1);
    __syncthreads();
    if (tid < NBKT) histT[tid * NB_S + k] = lh[tid];
}

__global__ __launch_bounds__(256) void k_scatter(const int* __restrict__ edges,
                                                 const int* __restrict__ offs,
                                                 int2* __restrict__ staging, int e) {
    __shared__ int cur[NBKT];
    int tid = threadIdx.x, k = blockIdx.x;
    if (tid < NBKT) cur[tid] = offs[tid * NB_S + k];
    __syncthreads();
    int chunk = (e + NB_S - 1) / NB_S;
    int i0 = k * chunk, i1 = min(i0 + chunk, e);
    for (int i = i0 + tid; i < i1; i += 256) {
        int s = edges[i];
        int d = edges[e + i];
        int p = atomicAdd(&cur[d >> BSH], 1);
        staging[p] = make_int2(s, d);
    }
}

__global__ __launch_bounds__(256) void k_bucket_fill(const int2* __restrict__ staging,
        const int* __restrict__ offs, int* __restrict__ rowptr,
        float* __restrict__ invd, int* __restrict__ adj, int n, int e) {
    __shared__ int ldeg[NPB];
    __shared__ int lrow[NPB];
    __shared__ int ps[256];
    __shared__ int lseg[SEG_CAP];
    int tid = threadIdx.x, b = blockIdx.x;
    int n0 = b << BSH;
    int nn = min(NPB, n - n0);
    int segBeg = offs[b * NB_S];
    int segEnd = (b == NBKT - 1) ? e : offs[(b + 1) * NB_S];

    ldeg[tid] = 0; ldeg[tid + 256] = 0;
    __syncthreads();
    for (int i = segBeg + tid; i < segEnd; i += 256)
        atomicAdd(&ldeg[staging[i].y - n0], 1);
    __syncthreads();

    int a0 = ldeg[2 * tid], a1 = ldeg[2 * tid + 1];
    int s = a0 + a1;
    ps[tid] = s;
    __syncthreads();
    for (int off = 1; off < 256; off <<= 1) {
        int t = (tid >= off) ? ps[tid - off] : 0;
        __syncthreads();
        ps[tid] += t;
        __syncthreads();
    }
    int excl = ps[tid] - s;
    lrow[2 * tid] = excl;
    lrow[2 * tid + 1] = excl + a0;
    __syncthreads();

    for (int j = tid; j < nn; j += 256) {
        rowptr[n0 + j] = segBeg + lrow[j];
        int d = ldeg[j];
        invd[n0 + j] = (d > 0) ? (1.0f / (float)d) : 0.0f;
    }
    if (b == NBKT - 1 && tid == 0) rowptr[n] = e;
    __syncthreads();

    for (int i = segBeg + tid; i < segEnd; i += 256) {
        int2 ed = staging[i];
        int p = atomicAdd(&lrow[ed.y - n0], 1);
        if (p < SEG_CAP) lseg[p] = ed.x;
        else adj[segBeg + p] = ed.x;
    }
    __syncthreads();

    int m = segEnd - segBeg; if (m > SEG_CAP) m = SEG_CAP;
    for (int p = tid; p < m; p += 256) adj[segBeg + p] = lseg[p];
}

// ---------------- aggregation ----------------

__global__ __launch_bounds__(256) void k_aggregate(const int* __restrict__ rowptr,
        const int* __restrict__ adj, const float* __restrict__ invd,
        const float* __restrict__ hin, float* __restrict__ agg, int n) {
    int wid = threadIdx.x >> 6, lane = threadIdx.x & 63;
    int node = blockIdx.x * 4 + wid;
    if (node >= n) return;
    int beg = rowptr[node], end = rowptr[node + 1];
    float acc = 0.0f;
    for (int e = beg; e < end; e += 8) {
        int idx[8];
        #pragma unroll
        for (int j = 0; j < 8; ++j) {
            int ee = e + j;
            idx[j] = adj[ee < end ? ee : end - 1];
        }
        float v[8];
        #pragma unroll
        for (int j = 0; j < 8; ++j) v[j] = hin[(size_t)idx[j] * HID_C + lane];
        #pragma unroll
        for (int j = 0; j < 8; ++j) acc += (e + j < end) ? v[j] : 0.0f;
    }
    agg[(size_t)node * HID_C + lane] = acc * invd[node];
}

// ------- LDS-staged GEMM, R4 structure + occupancy/conflict fixes ----------
// 64 rows x 64 cols, K=128 processed as two 64-K halves through a single
// 16 KB AT buffer (LDS 50 KB total -> 3 blocks/CU, launch_bounds(256,3)).
// AT layout k-major + XOR row swizzle: A[r][k] at AT[k*64 + (r ^ (4*(k>>2) & 60))].
//  - staging: 4 rows/wave x 16 chunks -> write banks exactly 2-way (free, m136)
//  - compute A-read: 4 unique b128 addrs/wave spanning 16 distinct banks (free)
// W staged once, stride 68 (pad +4): staging writes 2-way, reads 2-way.
// Inner loop identical to R4's proven pattern (4 A-b128 + 4 W-b128 + 64 FMA/kc).
// NOTE: R5/R6's register-direct (per-thread pointer) A-gather triggers a hipcc
// scratch pathology (2.5 GB scratch traffic at VGPR=64) — do not reintroduce.
// MODE 0: encoder  MODE 1: layer  MODE 2: pred (fused @W2+b2)

__device__ __forceinline__ float4 ld4(const float* p) { return *(const float4*)p; }

__device__ __forceinline__ void fma4x4(float4& C0, float4& C1, float4& C2, float4& C3,
                                       const float4 a, const float4 w) {
    C0.x = fmaf(a.x, w.x, C0.x); C0.y = fmaf(a.x, w.y, C0.y); C0.z = fmaf(a.x, w.z, C0.z); C0.w = fmaf(a.x, w.w, C0.w);
    C1.x = fmaf(a.y, w.x, C1.x); C1.y = fmaf(a.y, w.y, C1.y); C1.z = fmaf(a.y, w.z, C1.z); C1.w = fmaf(a.y, w.w, C1.w);
    C2.x = fmaf(a.z, w.x, C2.x); C2.y = fmaf(a.z, w.y, C2.y); C2.z = fmaf(a.z, w.z, C2.z); C2.w = fmaf(a.z, w.w, C2.w);
    C3.x = fmaf(a.w, w.x, C3.x); C3.y = fmaf(a.w, w.y, C3.y); C3.z = fmaf(a.w, w.z, C3.z); C3.w = fmaf(a.w, w.w, C3.w);
}

template<int MODE>
__global__ __launch_bounds__(256, 3) void k_gemm(
    const float* __restrict__ A1, const float* __restrict__ A2,
    const int* __restrict__ pidx,
    const float* __restrict__ Ws1, const float* __restrict__ Ws2,
    const float* __restrict__ bias, const float* __restrict__ W2p,
    const float* __restrict__ b2p,
    float* __restrict__ outp, int nrows)
{
    __shared__ float Wm[128 * WST];   // 34.8 KB, k-major, padded stride
    __shared__ float AT[64 * 64];     // 16 KB, one K-half, swizzled
    const int t = threadIdx.x;
    const int g0 = blockIdx.x * 64;

    // stage W (K=128), coalesced global read, 2-way LDS writes (stride 68)
    {
        int kw = t >> 4;              // 0..15
        int c4 = (t & 15) * 4;
        #pragma unroll
        for (int p = 0; p < 8; ++p) {
            int k = p * 16 + kw;
            float4 wv;
            if (MODE == 1) wv = (k < 64) ? ld4(Ws1 + k * 64 + c4) : ld4(Ws2 + (k - 64) * 64 + c4);
            else           wv = ld4(Ws1 + k * 64 + c4);
            *(float4*)&Wm[k * WST + c4] = wv;
        }
    }

    const int tc = t & 15, tr = t >> 4;
    const int tc4 = tc * 4, tr4 = tr * 4;
    const int sr = t >> 4;            // staging row-in-group (0..15)
    const int sc = t & 15;            // staging float4-chunk  (0..15)

    float4 C0 = make_float4(0.f, 0.f, 0.f, 0.f);
    float4 C1 = C0, C2 = C0, C3 = C0;

    #pragma unroll
    for (int H = 0; H < 2; ++H) {
        if (H) __syncthreads();       // protect AT before re-staging
        // stage A half H: rows p*16+sr, k-chunk sc (4 floats), transposed+swizzled
        #pragma unroll
        for (int p = 0; p < 4; ++p) {
            int r = p * 16 + sr;
            int g = g0 + r; if (g > nrows - 1) g = nrows - 1;
            const float* ptr;
            if (MODE == 0)      ptr = A1 + (size_t)g * 128 + H * 64 + sc * 4;
            else if (MODE == 1) ptr = (H == 0 ? A1 : A2) + (size_t)g * 64 + sc * 4;
            else { int idx = pidx[2 * g + H]; ptr = A1 + (size_t)idx * 64 + sc * 4; }
            float4 av = ld4(ptr);
            int rs = r ^ (sc * 4);            // row swizzle (sc*4 < 64)
            int base = sc * 256 + rs;         // (4*sc)*64 + rs
            AT[base      ] = av.x;
            AT[base +  64] = av.y;
            AT[base + 128] = av.z;
            AT[base + 192] = av.w;
        }
        __syncthreads();
        // compute half H
        #pragma unroll
        for (int kc = 0; kc < 16; ++kc) {
            int abase = kc * 256 + (tr4 ^ (kc * 4));
            const float* wb = &Wm[(H * 64 + 4 * kc) * WST + tc4];
            float4 a0 = ld4(&AT[abase      ]);   // rows tr4..tr4+3 @ k=4kc+0
            float4 w0 = ld4(wb);
            float4 a1 = ld4(&AT[abase +  64]);
            float4 w1 = ld4(wb + WST);
            float4 a2 = ld4(&AT[abase + 128]);
            float4 w2 = ld4(wb + 2 * WST);
            float4 a3 = ld4(&AT[abase + 192]);
            float4 w3 = ld4(wb + 3 * WST);
            fma4x4(C0, C1, C2, C3, a0, w0);
            fma4x4(C0, C1, C2, C3, a1, w1);
            fma4x4(C0, C1, C2, C3, a2, w2);
            fma4x4(C0, C1, C2, C3, a3, w3);
        }
    }

    float4 bv = ld4(bias + tc4);
    if (MODE == 2) {
        float4 w2v = ld4(W2p + tc4);
        float bb = b2p[0];
        #pragma unroll
        for (int i = 0; i < 4; ++i) {
            float4 Ci = (i == 0) ? C0 : (i == 1) ? C1 : (i == 2) ? C2 : C3;
            float zx = fmaxf(Ci.x + bv.x, 0.f);
            float zy = fmaxf(Ci.y + bv.y, 0.f);
            float zz = fmaxf(Ci.z + bv.z, 0.f);
            float zw = fmaxf(Ci.w + bv.w, 0.f);
            float v = zx * w2v.x + zy * w2v.y + zz * w2v.z + zw * w2v.w;
            v += __shfl_down(v, 8, 64);
            v += __shfl_down(v, 4, 64);
            v += __shfl_down(v, 2, 64);
            v += __shfl_down(v, 1, 64);
            if (tc == 0) {
                int g = g0 + tr4 + i;
                if (g < nrows) outp[g] = v + bb;
            }
        }
    } else {
        #pragma unroll
        for (int i = 0; i < 4; ++i) {
            float4 Ci = (i == 0) ? C0 : (i == 1) ? C1 : (i == 2) ? C2 : C3;
            int g = g0 + tr4 + i;
            if (g < nrows) {
                float4 o;
                o.x = fmaxf(Ci.x + bv.x, 0.f);
                o.y = fmaxf(Ci.y + bv.y, 0.f);
                o.z = fmaxf(Ci.z + bv.z, 0.f);
                o.w = fmaxf(Ci.w + bv.w, 0.f);
                *(float4*)&outp[(size_t)g * 64 + tc4] = o;
            }
        }
    }
}

// ---------------- launch ----------------

extern "C" void kernel_launch(void* const* d_in, const int* in_sizes, int n_in,
                              void* d_out, int out_size, void* d_ws, size_t ws_size,
                              hipStream_t stream) {
    const float* x    = (const float*)d_in[0];
    const int*   edges= (const int*)d_in[1];
    const int*   pair = (const int*)d_in[2];
    const float* encW = (const float*)d_in[3];
    const float* encb = (const float*)d_in[4];
    const float* Wl   = (const float*)d_in[5];
    const float* bl   = (const float*)d_in[6];
    const float* Wr   = (const float*)d_in[7];
    const float* W1   = (const float*)d_in[8];
    const float* b1   = (const float*)d_in[9];
    const float* W2   = (const float*)d_in[10];
    const float* b2   = (const float*)d_in[11];
    float* out = (float*)d_out;

    const int N = N_NODES_C, E = N_EDGES_C, P = N_PAIRS_C;
    const int* dst = edges + E;
    const int M = NBKT * NB_S;

    char* w = (char*)d_ws;
    auto alloc = [&](size_t bytes) { char* p = w; w += (bytes + 255) & ~(size_t)255; return p; };
    int*   rowptr = (int*)alloc((size_t)(N + 1) * 4);
    int*   histT  = (int*)alloc((size_t)M * 4);
    int*   offs   = (int*)alloc((size_t)M * 4);
    int*   bsums  = (int*)alloc(128 * 4);
    float* invd   = (float*)alloc((size_t)N * 4);
    int*   adj    = (int*)alloc((size_t)E * 4);
    float* h0     = (float*)alloc((size_t)N * HID_C * 4);
    float* h1     = (float*)alloc((size_t)N * HID_C * 4);
    float* agg    = (float*)alloc((size_t)N * HID_C * 4);
    int2*  staging= (int2*)agg;

    int nscan = (M + SCAN_ELEMS - 1) / SCAN_ELEMS;

    hipLaunchKernelGGL(k_hist, dim3(NB_S), dim3(256), 0, stream, dst, histT, E);
    hipLaunchKernelGGL(k_scan_partial, dim3(nscan), dim3(SCAN_TPB), 0, stream, histT, offs, bsums, M);
    hipLaunchKernelGGL(k_scan_blocks, dim3(1), dim3(128), 0, stream, bsums, nscan);
    hipLaunchKernelGGL(k_scan_addg, dim3((M + 255) / 256), dim3(256), 0, stream, offs, bsums, M);
    hipLaunchKernelGGL(k_scatter, dim3(NB_S), dim3(256), 0, stream, edges, offs, staging, E);
    hipLaunchKernelGGL(k_bucket_fill, dim3(NBKT), dim3(256), 0, stream, staging, offs, rowptr, invd, adj, N, E);

    const int NB_N = (N + 63) / 64;
    const int NB_P = (P + 63) / 64;

    k_gemm<0><<<dim3(NB_N), dim3(256), 0, stream>>>(
        x, nullptr, nullptr, encW, nullptr, encb, nullptr, nullptr, h0, N);

    float* hc = h0; float* hn = h1;
    for (int l = 0; l < 3; l++) {
        hipLaunchKernelGGL(k_aggregate, dim3((N + 3) / 4), dim3(256), 0, stream,
                           rowptr, adj, invd, hc, agg, N);
        k_gemm<1><<<dim3(NB_N), dim3(256), 0, stream>>>(
            agg, hc, nullptr, Wl + (size_t)l * 64 * 64, Wr + (size_t)l * 64 * 64,
            bl + (size_t)l * 64, nullptr, nullptr, hn, N);
        float* tswap = hc; hc = hn; hn = tswap;
    }

    k_gemm<2><<<dim3(NB_P), dim3(256), 0, stream>>>(
        hc, nullptr, pair, W1, nullptr, b1, W2, b2, out, P);
}

// Round 8
// 11922.305 us; speedup vs baseline: 1.0118x; 1.0118x over previous
//
#include <hip/hip_runtime.h>
#include <cstdint>
#include <cstddef>

#define N_NODES_C 100000
#define N_EDGES_C 1250000
#define N_PAIRS_C 200000
#define IN_DIM_C 128
#define HID_C 64

// graph-build geometry
#define NB_S 256
#define BSH 9
#define NPB 512
#define NBKT 196
#define SEG_CAP 8192

// ---------------- scan helpers ----------------

#define SCAN_TPB 256
#define SCAN_IPT 4
#define SCAN_ELEMS 1024

__global__ void k_scan_partial(const int* __restrict__ in, int* __restrict__ outp,
                               int* __restrict__ blocksums, int n) {
    __shared__ int sd[SCAN_TPB];
    int tid = threadIdx.x;
    int base = blockIdx.x * SCAN_ELEMS + tid * SCAN_IPT;
    int v[SCAN_IPT]; int s = 0;
    for (int k = 0; k < SCAN_IPT; k++) { int idx = base + k; v[k] = (idx < n) ? in[idx] : 0; s += v[k]; }
    sd[tid] = s;
    __syncthreads();
    for (int off = 1; off < SCAN_TPB; off <<= 1) {
        int t = (tid >= off) ? sd[tid - off] : 0;
        __syncthreads();
        sd[tid] += t;
        __syncthreads();
    }
    int excl = sd[tid] - s;
    for (int k = 0; k < SCAN_IPT; k++) { int idx = base + k; if (idx < n) outp[idx] = excl; excl += v[k]; }
    if (tid == SCAN_TPB - 1) blocksums[blockIdx.x] = sd[tid];
}

__global__ void k_scan_blocks(int* __restrict__ bs, int nb) {
    __shared__ int sd[128];
    int t = threadIdx.x;
    int v = (t < nb) ? bs[t] : 0;
    sd[t] = v;
    __syncthreads();
    for (int off = 1; off < 128; off <<= 1) {
        int u = (t >= off) ? sd[t - off] : 0;
        __syncthreads();
        sd[t] += u;
        __syncthreads();
    }
    if (t < nb) bs[t] = sd[t] - v;
}

__global__ void k_scan_addg(int* __restrict__ arr, const int* __restrict__ bs, int n) {
    int i = blockIdx.x * blockDim.x + threadIdx.x;
    if (i < n) arr[i] += bs[i >> 10];
}

// ---------------- graph build: two-level counting sort ----------------

__global__ __launch_bounds__(256) void k_hist(const int* __restrict__ dst,
                                              int* __restrict__ histT, int e) {
    __shared__ int lh[NBKT];
    int tid = threadIdx.x, k = blockIdx.x;
    if (tid < NBKT) lh[tid] = 0;
    __syncthreads();
    int chunk = (e + NB_S - 1) / NB_S;
    int i0 = k * chunk, i1 = min(i0 + chunk, e);
    for (int i = i0 + tid; i < i1; i += 256) atomicAdd(&lh[dst[i] >> BSH], 1);
    __syncthreads();
    if (tid < NBKT) histT[tid * NB_S + k] = lh[tid];
}

__global__ __launch_bounds__(256) void k_scatter(const int* __restrict__ edges,
                                                 const int* __restrict__ offs,
                                                 int2* __restrict__ staging, int e) {
    __shared__ int cur[NBKT];
    int tid = threadIdx.x, k = blockIdx.x;
    if (tid < NBKT) cur[tid] = offs[tid * NB_S + k];
    __syncthreads();
    int chunk = (e + NB_S - 1) / NB_S;
    int i0 = k * chunk, i1 = min(i0 + chunk, e);
    for (int i = i0 + tid; i < i1; i += 256) {
        int s = edges[i];
        int d = edges[e + i];
        int p = atomicAdd(&cur[d >> BSH], 1);
        staging[p] = make_int2(s, d);
    }
}

__global__ __launch_bounds__(256) void k_bucket_fill(const int2* __restrict__ staging,
        const int* __restrict__ offs, int* __restrict__ rowptr,
        float* __restrict__ invd, int* __restrict__ adj, int n, int e) {
    __shared__ int ldeg[NPB];
    __shared__ int lrow[NPB];
    __shared__ int ps[256];
    __shared__ int lseg[SEG_CAP];
    int tid = threadIdx.x, b = blockIdx.x;
    int n0 = b << BSH;
    int nn = min(NPB, n - n0);
    int segBeg = offs[b * NB_S];
    int segEnd = (b == NBKT - 1) ? e : offs[(b + 1) * NB_S];

    ldeg[tid] = 0; ldeg[tid + 256] = 0;
    __syncthreads();
    for (int i = segBeg + tid; i < segEnd; i += 256)
        atomicAdd(&ldeg[staging[i].y - n0], 1);
    __syncthreads();

    int a0 = ldeg[2 * tid], a1 = ldeg[2 * tid + 1];
    int s = a0 + a1;
    ps[tid] = s;
    __syncthreads();
    for (int off = 1; off < 256; off <<= 1) {
        int t = (tid >= off) ? ps[tid - off] : 0;
        __syncthreads();
        ps[tid] += t;
        __syncthreads();
    }
    int excl = ps[tid] - s;
    lrow[2 * tid] = excl;
    lrow[2 * tid + 1] = excl + a0;
    __syncthreads();

    for (int j = tid; j < nn; j += 256) {
        rowptr[n0 + j] = segBeg + lrow[j];
        int d = ldeg[j];
        invd[n0 + j] = (d > 0) ? (1.0f / (float)d) : 0.0f;
    }
    if (b == NBKT - 1 && tid == 0) rowptr[n] = e;
    __syncthreads();

    for (int i = segBeg + tid; i < segEnd; i += 256) {
        int2 ed = staging[i];
        int p = atomicAdd(&lrow[ed.y - n0], 1);
        if (p < SEG_CAP) lseg[p] = ed.x;
        else adj[segBeg + p] = ed.x;
    }
    __syncthreads();

    int m = segEnd - segBeg; if (m > SEG_CAP) m = SEG_CAP;
    for (int p = tid; p < m; p += 256) adj[segBeg + p] = lseg[p];
}

// ---------------- aggregation ----------------

__global__ __launch_bounds__(256) void k_aggregate(const int* __restrict__ rowptr,
        const int* __restrict__ adj, const float* __restrict__ invd,
        const float* __restrict__ hin, float* __restrict__ agg, int n) {
    int wid = threadIdx.x >> 6, lane = threadIdx.x & 63;
    int node = blockIdx.x * 4 + wid;
    if (node >= n) return;
    int beg = rowptr[node], end = rowptr[node + 1];
    float acc = 0.0f;
    for (int e = beg; e < end; e += 8) {
        int idx[8];
        #pragma unroll
        for (int j = 0; j < 8; ++j) {
            int ee = e + j;
            idx[j] = adj[ee < end ? ee : end - 1];
        }
        float v[8];
        #pragma unroll
        for (int j = 0; j < 8; ++j) v[j] = hin[(size_t)idx[j] * HID_C + lane];
        #pragma unroll
        for (int j = 0; j < 8; ++j) acc += (e + j < end) ? v[j] : 0.0f;
    }
    agg[(size_t)node * HID_C + lane] = acc * invd[node];
}

// ------- LDS-staged GEMM: R4 inner loop verbatim + occupancy/conflict fixes --
// 64 rows x 64 cols, K=128 as two 64-K halves through one 16 KB AT buffer.
// LDS = 32 KB (W) + 16 KB (AT) = 48 KB -> 3 blocks/CU (launch_bounds(256,3)).
// AT layout: k-major, NO swizzle: A[r][k] at AT[(k>>2)*256 + (k&3)*64 + r].
//  - staging lane-row-major (lane = row): write banks = r%32, exactly 2-way (free)
//  - compute read ld4(&AT[kc*256 + i*64 + tr4]): 4 distinct b128 quads +
//    16-lane broadcast -> conflict-free
// W staged k-major stride 64, byte-identical to R4 (proven).
// *** CODEGEN RULE (R5/R6/R7 post-mortems): NO address-taken float4 locals in
// the hot loop — no helper functions with float4& params, no pointer casts of
// locals, no variably-indexed local arrays. hipcc leaves the alloca in scratch
// -> multi-GB HBM scratch traffic (measured 5-6.3 GB/dispatch, VALUBusy ~1%).
// Plain named locals + .xyzw fmaf chains only. ***
// MODE 0: encoder  MODE 1: layer  MODE 2: pred (fused @W2+b2)

__device__ __forceinline__ float4 ld4(const float* p) { return *(const float4*)p; }

template<int MODE>
__global__ __launch_bounds__(256, 3) void k_gemm(
    const float* __restrict__ A1, const float* __restrict__ A2,
    const int* __restrict__ pidx,
    const float* __restrict__ Ws1, const float* __restrict__ Ws2,
    const float* __restrict__ bias, const float* __restrict__ W2p,
    const float* __restrict__ b2p,
    float* __restrict__ outp, int nrows)
{
    __shared__ float Wm[128 * 64];   // 32 KB, k-major (R4-identical)
    __shared__ float AT[64 * 64];    // 16 KB, one K-half, no swizzle
    const int t = threadIdx.x;
    const int g0 = blockIdx.x * 64;

    // stage W (K=128), R4-identical
    #pragma unroll
    for (int p = 0; p < 8; ++p) {
        int k = p * 16 + (t >> 4);
        int c4 = (t & 15) * 4;
        float4 wv;
        if (MODE == 1) wv = (k < 64) ? ld4(Ws1 + k * 64 + c4) : ld4(Ws2 + (k - 64) * 64 + c4);
        else           wv = ld4(Ws1 + k * 64 + c4);
        *(float4*)&Wm[k * 64 + c4] = wv;
    }

    const int tc = t & 15, tr = t >> 4;
    const int tc4 = tc * 4, tr4 = tr * 4;
    const int srow = t & 63;          // staging: lane = row
    const int scw  = t >> 6;          // staging: chunk-column group (0..3)

    float4 acc0 = {0, 0, 0, 0}, acc1 = acc0, acc2 = acc0, acc3 = acc0;

    #pragma unroll
    for (int H = 0; H < 2; ++H) {
        if (H) __syncthreads();       // protect AT before re-staging
        // stage A half H: thread = row srow, chunks scw+4q (q=0..3)
        {
            int g = g0 + srow; if (g > nrows - 1) g = nrows - 1;
            const float* rowp;
            if (MODE == 0)      rowp = A1 + (size_t)g * 128 + H * 64;
            else if (MODE == 1) rowp = (H == 0 ? A1 : A2) + (size_t)g * 64;
            else { int idx = pidx[2 * g + H]; rowp = A1 + (size_t)idx * 64; }
            #pragma unroll
            for (int q = 0; q < 4; ++q) {
                int c = scw + 4 * q;
                float4 av = ld4(rowp + c * 4);
                int base = c * 256 + srow;
                AT[base      ] = av.x;
                AT[base +  64] = av.y;
                AT[base + 128] = av.z;
                AT[base + 192] = av.w;
            }
        }
        __syncthreads();
        // compute half H — R4 inner loop verbatim (abase without swizzle)
        #pragma unroll
        for (int kc = 0; kc < 16; ++kc) {
            int abase = kc * 256 + tr4;
            int wbase = (H * 64 + 4 * kc) * 64 + tc4;
            #pragma unroll
            for (int i = 0; i < 4; ++i) {
                float4 aw = ld4(&AT[abase + i * 64]);
                float4 ww = ld4(&Wm[wbase + i * 64]);
                acc0.x = fmaf(aw.x, ww.x, acc0.x); acc0.y = fmaf(aw.x, ww.y, acc0.y);
                acc0.z = fmaf(aw.x, ww.z, acc0.z); acc0.w = fmaf(aw.x, ww.w, acc0.w);
                acc1.x = fmaf(aw.y, ww.x, acc1.x); acc1.y = fmaf(aw.y, ww.y, acc1.y);
                acc1.z = fmaf(aw.y, ww.z, acc1.z); acc1.w = fmaf(aw.y, ww.w, acc1.w);
                acc2.x = fmaf(aw.z, ww.x, acc2.x); acc2.y = fmaf(aw.z, ww.y, acc2.y);
                acc2.z = fmaf(aw.z, ww.z, acc2.z); acc2.w = fmaf(aw.z, ww.w, acc2.w);
                acc3.x = fmaf(aw.w, ww.x, acc3.x); acc3.y = fmaf(aw.w, ww.y, acc3.y);
                acc3.z = fmaf(aw.w, ww.z, acc3.z); acc3.w = fmaf(aw.w, ww.w, acc3.w);
            }
        }
    }

    float4 bv = ld4(bias + tc4);
    float4 accs[4] = {acc0, acc1, acc2, acc3};
    if (MODE == 2) {
        float4 w2 = ld4(W2p + tc4);
        float bb = b2p[0];
        #pragma unroll
        for (int i = 0; i < 4; ++i) {
            float zx = fmaxf(accs[i].x + bv.x, 0.f);
            float zy = fmaxf(accs[i].y + bv.y, 0.f);
            float zz = fmaxf(accs[i].z + bv.z, 0.f);
            float zw = fmaxf(accs[i].w + bv.w, 0.f);
            float v = zx * w2.x + zy * w2.y + zz * w2.z + zw * w2.w;
            v += __shfl_down(v, 8, 64);
            v += __shfl_down(v, 4, 64);
            v += __shfl_down(v, 2, 64);
            v += __shfl_down(v, 1, 64);
            if (tc == 0) {
                int g = g0 + tr4 + i;
                if (g < nrows) outp[g] = v + bb;
            }
        }
    } else {
        #pragma unroll
        for (int i = 0; i < 4; ++i) {
            int g = g0 + tr4 + i;
            if (g < nrows) {
                float4 o;
                o.x = fmaxf(accs[i].x + bv.x, 0.f);
                o.y = fmaxf(accs[i].y + bv.y, 0.f);
                o.z = fmaxf(accs[i].z + bv.z, 0.f);
                o.w = fmaxf(accs[i].w + bv.w, 0.f);
                *(float4*)&outp[(size_t)g * 64 + tc4] = o;
            }
        }
    }
}

// ---------------- launch ----------------

extern "C" void kernel_launch(void* const* d_in, const int* in_sizes, int n_in,
                              void* d_out, int out_size, void* d_ws, size_t ws_size,
                              hipStream_t stream) {
    const float* x    = (const float*)d_in[0];
    const int*   edges= (const int*)d_in[1];
    const int*   pair = (const int*)d_in[2];
    const float* encW = (const float*)d_in[3];
    const float* encb = (const float*)d_in[4];
    const float* Wl   = (const float*)d_in[5];
    const float* bl   = (const float*)d_in[6];
    const float* Wr   = (const float*)d_in[7];
    const float* W1   = (const float*)d_in[8];
    const float* b1   = (const float*)d_in[9];
    const float* W2   = (const float*)d_in[10];
    const float* b2   = (const float*)d_in[11];
    float* out = (float*)d_out;

    const int N = N_NODES_C, E = N_EDGES_C, P = N_PAIRS_C;
    const int* dst = edges + E;
    const int M = NBKT * NB_S;

    char* w = (char*)d_ws;
    auto alloc = [&](size_t bytes) { char* p = w; w += (bytes + 255) & ~(size_t)255; return p; };
    int*   rowptr = (int*)alloc((size_t)(N + 1) * 4);
    int*   histT  = (int*)alloc((size_t)M * 4);
    int*   offs   = (int*)alloc((size_t)M * 4);
    int*   bsums  = (int*)alloc(128 * 4);
    float* invd   = (float*)alloc((size_t)N * 4);
    int*   adj    = (int*)alloc((size_t)E * 4);
    float* h0     = (float*)alloc((size_t)N * HID_C * 4);
    float* h1     = (float*)alloc((size_t)N * HID_C * 4);
    float* agg    = (float*)alloc((size_t)N * HID_C * 4);
    int2*  staging= (int2*)agg;

    int nscan = (M + SCAN_ELEMS - 1) / SCAN_ELEMS;

    hipLaunchKernelGGL(k_hist, dim3(NB_S), dim3(256), 0, stream, dst, histT, E);
    hipLaunchKernelGGL(k_scan_partial, dim3(nscan), dim3(SCAN_TPB), 0, stream, histT, offs, bsums, M);
    hipLaunchKernelGGL(k_scan_blocks, dim3(1), dim3(128), 0, stream, bsums, nscan);
    hipLaunchKernelGGL(k_scan_addg, dim3((M + 255) / 256), dim3(256), 0, stream, offs, bsums, M);
    hipLaunchKernelGGL(k_scatter, dim3(NB_S), dim3(256), 0, stream, edges, offs, staging, E);
    hipLaunchKernelGGL(k_bucket_fill, dim3(NBKT), dim3(256), 0, stream, staging, offs, rowptr, invd, adj, N, E);

    const int NB_N = (N + 63) / 64;
    const int NB_P = (P + 63) / 64;

    k_gemm<0><<<dim3(NB_N), dim3(256), 0, stream>>>(
        x, nullptr, nullptr, encW, nullptr, encb, nullptr, nullptr, h0, N);

    float* hc = h0; float* hn = h1;
    for (int l = 0; l < 3; l++) {
        hipLaunchKernelGGL(k_aggregate, dim3((N + 3) / 4), dim3(256), 0, stream,
                           rowptr, adj, invd, hc, agg, N);
        k_gemm<1><<<dim3(NB_N), dim3(256), 0, stream>>>(
            agg, hc, nullptr, Wl + (size_t)l * 64 * 64, Wr + (size_t)l * 64 * 64,
            bl + (size_t)l * 64, nullptr, nullptr, hn, N);
        float* tswap = hc; hc = hn; hn = tswap;
    }

    k_gemm<2><<<dim3(NB_P), dim3(256), 0, stream>>>(
        hc, nullptr, pair, W1, nullptr, b1, W2, b2, out, P);
}

// Round 9
// 462.799 us; speedup vs baseline: 26.0643x; 25.7613x over previous
//
#include <hip/hip_runtime.h>
#include <cstdint>
#include <cstddef>

#define N_NODES_C 100000
#define N_EDGES_C 1250000
#define N_PAIRS_C 200000
#define IN_DIM_C 128
#define HID_C 64

// graph-build geometry
#define NB_S 256
#define BSH 9
#define NPB 512
#define NBKT 196
#define SEG_CAP 8192

// ---------------- scan helpers ----------------

#define SCAN_TPB 256
#define SCAN_IPT 4
#define SCAN_ELEMS 1024

__global__ void k_scan_partial(const int* __restrict__ in, int* __restrict__ outp,
                               int* __restrict__ blocksums, int n) {
    __shared__ int sd[SCAN_TPB];
    int tid = threadIdx.x;
    int base = blockIdx.x * SCAN_ELEMS + tid * SCAN_IPT;
    int v[SCAN_IPT]; int s = 0;
    for (int k = 0; k < SCAN_IPT; k++) { int idx = base + k; v[k] = (idx < n) ? in[idx] : 0; s += v[k]; }
    sd[tid] = s;
    __syncthreads();
    for (int off = 1; off < SCAN_TPB; off <<= 1) {
        int t = (tid >= off) ? sd[tid - off] : 0;
        __syncthreads();
        sd[tid] += t;
        __syncthreads();
    }
    int excl = sd[tid] - s;
    for (int k = 0; k < SCAN_IPT; k++) { int idx = base + k; if (idx < n) outp[idx] = excl; excl += v[k]; }
    if (tid == SCAN_TPB - 1) blocksums[blockIdx.x] = sd[tid];
}

__global__ void k_scan_blocks(int* __restrict__ bs, int nb) {
    __shared__ int sd[128];
    int t = threadIdx.x;
    int v = (t < nb) ? bs[t] : 0;
    sd[t] = v;
    __syncthreads();
    for (int off = 1; off < 128; off <<= 1) {
        int u = (t >= off) ? sd[t - off] : 0;
        __syncthreads();
        sd[t] += u;
        __syncthreads();
    }
    if (t < nb) bs[t] = sd[t] - v;
}

__global__ void k_scan_addg(int* __restrict__ arr, const int* __restrict__ bs, int n) {
    int i = blockIdx.x * blockDim.x + threadIdx.x;
    if (i < n) arr[i] += bs[i >> 10];
}

// ---------------- graph build: two-level counting sort ----------------

__global__ __launch_bounds__(256) void k_hist(const int* __restrict__ dst,
                                              int* __restrict__ histT, int e) {
    __shared__ int lh[NBKT];
    int tid = threadIdx.x, k = blockIdx.x;
    if (tid < NBKT) lh[tid] = 0;
    __syncthreads();
    int chunk = (e + NB_S - 1) / NB_S;
    int i0 = k * chunk, i1 = min(i0 + chunk, e);
    for (int i = i0 + tid; i < i1; i += 256) atomicAdd(&lh[dst[i] >> BSH], 1);
    __syncthreads();
    if (tid < NBKT) histT[tid * NB_S + k] = lh[tid];
}

__global__ __launch_bounds__(256) void k_scatter(const int* __restrict__ edges,
                                                 const int* __restrict__ offs,
                                                 int2* __restrict__ staging, int e) {
    __shared__ int cur[NBKT];
    int tid = threadIdx.x, k = blockIdx.x;
    if (tid < NBKT) cur[tid] = offs[tid * NB_S + k];
    __syncthreads();
    int chunk = (e + NB_S - 1) / NB_S;
    int i0 = k * chunk, i1 = min(i0 + chunk, e);
    for (int i = i0 + tid; i < i1; i += 256) {
        int s = edges[i];
        int d = edges[e + i];
        int p = atomicAdd(&cur[d >> BSH], 1);
        staging[p] = make_int2(s, d);
    }
}

__global__ __launch_bounds__(256) void k_bucket_fill(const int2* __restrict__ staging,
        const int* __restrict__ offs, int* __restrict__ rowptr,
        float* __restrict__ invd, int* __restrict__ adj, int n, int e) {
    __shared__ int ldeg[NPB];
    __shared__ int lrow[NPB];
    __shared__ int ps[256];
    __shared__ int lseg[SEG_CAP];
    int tid = threadIdx.x, b = blockIdx.x;
    int n0 = b << BSH;
    int nn = min(NPB, n - n0);
    int segBeg = offs[b * NB_S];
    int segEnd = (b == NBKT - 1) ? e : offs[(b + 1) * NB_S];

    ldeg[tid] = 0; ldeg[tid + 256] = 0;
    __syncthreads();
    for (int i = segBeg + tid; i < segEnd; i += 256)
        atomicAdd(&ldeg[staging[i].y - n0], 1);
    __syncthreads();

    int a0 = ldeg[2 * tid], a1 = ldeg[2 * tid + 1];
    int s = a0 + a1;
    ps[tid] = s;
    __syncthreads();
    for (int off = 1; off < 256; off <<= 1) {
        int t = (tid >= off) ? ps[tid - off] : 0;
        __syncthreads();
        ps[tid] += t;
        __syncthreads();
    }
    int excl = ps[tid] - s;
    lrow[2 * tid] = excl;
    lrow[2 * tid + 1] = excl + a0;
    __syncthreads();

    for (int j = tid; j < nn; j += 256) {
        rowptr[n0 + j] = segBeg + lrow[j];
        int d = ldeg[j];
        invd[n0 + j] = (d > 0) ? (1.0f / (float)d) : 0.0f;
    }
    if (b == NBKT - 1 && tid == 0) rowptr[n] = e;
    __syncthreads();

    for (int i = segBeg + tid; i < segEnd; i += 256) {
        int2 ed = staging[i];
        int p = atomicAdd(&lrow[ed.y - n0], 1);
        if (p < SEG_CAP) lseg[p] = ed.x;
        else adj[segBeg + p] = ed.x;
    }
    __syncthreads();

    int m = segEnd - segBeg; if (m > SEG_CAP) m = SEG_CAP;
    for (int p = tid; p < m; p += 256) adj[segBeg + p] = lseg[p];
}

// ---------------- aggregation ----------------

__global__ __launch_bounds__(256) void k_aggregate(const int* __restrict__ rowptr,
        const int* __restrict__ adj, const float* __restrict__ invd,
        const float* __restrict__ hin, float* __restrict__ agg, int n) {
    int wid = threadIdx.x >> 6, lane = threadIdx.x & 63;
    int node = blockIdx.x * 4 + wid;
    if (node >= n) return;
    int beg = rowptr[node], end = rowptr[node + 1];
    float acc = 0.0f;
    for (int e = beg; e < end; e += 8) {
        int idx[8];
        #pragma unroll
        for (int j = 0; j < 8; ++j) {
            int ee = e + j;
            idx[j] = adj[ee < end ? ee : end - 1];
        }
        float v[8];
        #pragma unroll
        for (int j = 0; j < 8; ++j) v[j] = hin[(size_t)idx[j] * HID_C + lane];
        #pragma unroll
        for (int j = 0; j < 8; ++j) acc += (e + j < end) ? v[j] : 0.0f;
    }
    agg[(size_t)node * HID_C + lane] = acc * invd[node];
}

// ---------------- tiled GEMM (64 rows x 64 cols, K=128, thread = 4x4 tile) ----
// R4 PROVEN ARTIFACT — byte-identical resubmission. 65 us pred GEMM, 44 MB
// fetch, VGPR 92, no scratch. Every deviation tried (R5-R8: register-direct A,
// two-half AT, launch_bounds(256,3/4)) triggered a hipcc scratch pathology
// (1.5-6.3 GB HBM scratch traffic per dispatch, VALUBusy ~1%). DO NOT MODIFY
// THIS KERNEL without an isolated single-variable probe.
// MODE 0: encoder  MODE 1: layer  MODE 2: pred (fused @W2+b2)

__device__ __forceinline__ float4 ld4(const float* p) { return *(const float4*)p; }

template<int MODE>
__global__ __launch_bounds__(256, 2) void k_gemm(
    const float* __restrict__ A1, const float* __restrict__ A2,
    const int* __restrict__ pidx,
    const float* __restrict__ Ws1, const float* __restrict__ Ws2,
    const float* __restrict__ bias, const float* __restrict__ W2p,
    const float* __restrict__ b2p,
    float* __restrict__ outp, int nrows)
{
    __shared__ float AT[128 * 64];   // 32 KB, transposed+swizzled
    __shared__ float Wm[128 * 64];   // 32 KB, k-major
    const int t = threadIdx.x;
    const int g0 = blockIdx.x * 64;

    #pragma unroll
    for (int p = 0; p < 8; ++p) {
        int k = p * 16 + (t >> 4);
        int c4 = (t & 15) * 4;
        float4 wv;
        if (MODE == 1) wv = (k < 64) ? ld4(Ws1 + k * 64 + c4) : ld4(Ws2 + (k - 64) * 64 + c4);
        else           wv = ld4(Ws1 + k * 64 + c4);
        *(float4*)&Wm[k * 64 + c4] = wv;
    }
    #pragma unroll
    for (int p = 0; p < 8; ++p) {
        int r = p * 8 + (t >> 5);
        int c = t & 31;
        int g = g0 + r; if (g > nrows - 1) g = nrows - 1;
        const float* ptr;
        if (MODE == 0)      ptr = A1 + (size_t)g * 128 + c * 4;
        else if (MODE == 1) ptr = (c < 16) ? (A1 + (size_t)g * 64 + c * 4)
                                           : (A2 + (size_t)g * 64 + (c - 16) * 4);
        else { int idx = pidx[2 * g + (c >> 4)]; ptr = A1 + (size_t)idx * 64 + (c & 15) * 4; }
        float4 av = ld4(ptr);
        int rs = r ^ ((c & 15) * 4);
        int base = c * 256 + rs;
        AT[base      ] = av.x;
        AT[base +  64] = av.y;
        AT[base + 128] = av.z;
        AT[base + 192] = av.w;
    }
    __syncthreads();

    const int tc = t & 15, tr = t >> 4;
    const int tc4 = tc * 4, tr4 = tr * 4;
    float4 acc0 = {0, 0, 0, 0}, acc1 = acc0, acc2 = acc0, acc3 = acc0;

    #pragma unroll 4
    for (int kc = 0; kc < 32; ++kc) {
        int abase = kc * 256 + (tr4 ^ ((kc & 15) * 4));
        int wbase = kc * 256 + tc4;
        #pragma unroll
        for (int i = 0; i < 4; ++i) {
            float4 aw = ld4(&AT[abase + i * 64]);
            float4 ww = ld4(&Wm[wbase + i * 64]);
            acc0.x = fmaf(aw.x, ww.x, acc0.x); acc0.y = fmaf(aw.x, ww.y, acc0.y);
            acc0.z = fmaf(aw.x, ww.z, acc0.z); acc0.w = fmaf(aw.x, ww.w, acc0.w);
            acc1.x = fmaf(aw.y, ww.x, acc1.x); acc1.y = fmaf(aw.y, ww.y, acc1.y);
            acc1.z = fmaf(aw.y, ww.z, acc1.z); acc1.w = fmaf(aw.y, ww.w, acc1.w);
            acc2.x = fmaf(aw.z, ww.x, acc2.x); acc2.y = fmaf(aw.z, ww.y, acc2.y);
            acc2.z = fmaf(aw.z, ww.z, acc2.z); acc2.w = fmaf(aw.z, ww.w, acc2.w);
            acc3.x = fmaf(aw.w, ww.x, acc3.x); acc3.y = fmaf(aw.w, ww.y, acc3.y);
            acc3.z = fmaf(aw.w, ww.z, acc3.z); acc3.w = fmaf(aw.w, ww.w, acc3.w);
        }
    }

    float4 bv = ld4(bias + tc4);
    float4 accs[4] = {acc0, acc1, acc2, acc3};
    if (MODE == 2) {
        float4 w2 = ld4(W2p + tc4);
        float bb = b2p[0];
        #pragma unroll
        for (int i = 0; i < 4; ++i) {
            float zx = fmaxf(accs[i].x + bv.x, 0.f);
            float zy = fmaxf(accs[i].y + bv.y, 0.f);
            float zz = fmaxf(accs[i].z + bv.z, 0.f);
            float zw = fmaxf(accs[i].w + bv.w, 0.f);
            float v = zx * w2.x + zy * w2.y + zz * w2.z + zw * w2.w;
            v += __shfl_down(v, 8, 64);
            v += __shfl_down(v, 4, 64);
            v += __shfl_down(v, 2, 64);
            v += __shfl_down(v, 1, 64);
            if (tc == 0) {
                int g = g0 + tr4 + i;
                if (g < nrows) outp[g] = v + bb;
            }
        }
    } else {
        #pragma unroll
        for (int i = 0; i < 4; ++i) {
            int g = g0 + tr4 + i;
            if (g < nrows) {
                float4 o;
                o.x = fmaxf(accs[i].x + bv.x, 0.f);
                o.y = fmaxf(accs[i].y + bv.y, 0.f);
                o.z = fmaxf(accs[i].z + bv.z, 0.f);
                o.w = fmaxf(accs[i].w + bv.w, 0.f);
                *(float4*)&outp[(size_t)g * 64 + tc4] = o;
            }
        }
    }
}

// ---------------- launch ----------------

extern "C" void kernel_launch(void* const* d_in, const int* in_sizes, int n_in,
                              void* d_out, int out_size, void* d_ws, size_t ws_size,
                              hipStream_t stream) {
    const float* x    = (const float*)d_in[0];
    const int*   edges= (const int*)d_in[1];
    const int*   pair = (const int*)d_in[2];
    const float* encW = (const float*)d_in[3];
    const float* encb = (const float*)d_in[4];
    const float* Wl   = (const float*)d_in[5];
    const float* bl   = (const float*)d_in[6];
    const float* Wr   = (const float*)d_in[7];
    const float* W1   = (const float*)d_in[8];
    const float* b1   = (const float*)d_in[9];
    const float* W2   = (const float*)d_in[10];
    const float* b2   = (const float*)d_in[11];
    float* out = (float*)d_out;

    const int N = N_NODES_C, E = N_EDGES_C, P = N_PAIRS_C;
    const int* dst = edges + E;
    const int M = NBKT * NB_S;

    char* w = (char*)d_ws;
    auto alloc = [&](size_t bytes) { char* p = w; w += (bytes + 255) & ~(size_t)255; return p; };
    int*   rowptr = (int*)alloc((size_t)(N + 1) * 4);
    int*   histT  = (int*)alloc((size_t)M * 4);
    int*   offs   = (int*)alloc((size_t)M * 4);
    int*   bsums  = (int*)alloc(128 * 4);
    float* invd   = (float*)alloc((size_t)N * 4);
    int*   adj    = (int*)alloc((size_t)E * 4);
    float* h0     = (float*)alloc((size_t)N * HID_C * 4);
    float* h1     = (float*)alloc((size_t)N * HID_C * 4);
    float* agg    = (float*)alloc((size_t)N * HID_C * 4);
    int2*  staging= (int2*)agg;

    int nscan = (M + SCAN_ELEMS - 1) / SCAN_ELEMS;

    hipLaunchKernelGGL(k_hist, dim3(NB_S), dim3(256), 0, stream, dst, histT, E);
    hipLaunchKernelGGL(k_scan_partial, dim3(nscan), dim3(SCAN_TPB), 0, stream, histT, offs, bsums, M);
    hipLaunchKernelGGL(k_scan_blocks, dim3(1), dim3(128), 0, stream, bsums, nscan);
    hipLaunchKernelGGL(k_scan_addg, dim3((M + 255) / 256), dim3(256), 0, stream, offs, bsums, M);
    hipLaunchKernelGGL(k_scatter, dim3(NB_S), dim3(256), 0, stream, edges, offs, staging, E);
    hipLaunchKernelGGL(k_bucket_fill, dim3(NBKT), dim3(256), 0, stream, staging, offs, rowptr, invd, adj, N, E);

    const int NB_N = (N + 63) / 64;
    const int NB_P = (P + 63) / 64;

    k_gemm<0><<<dim3(NB_N), dim3(256), 0, stream>>>(
        x, nullptr, nullptr, encW, nullptr, encb, nullptr, nullptr, h0, N);

    float* hc = h0; float* hn = h1;
    for (int l = 0; l < 3; l++) {
        hipLaunchKernelGGL(k_aggregate, dim3((N + 3) / 4), dim3(256), 0, stream,
                           rowptr, adj, invd, hc, agg, N);
        k_gemm<1><<<dim3(NB_N), dim3(256), 0, stream>>>(
            agg, hc, nullptr, Wl + (size_t)l * 64 * 64, Wr + (size_t)l * 64 * 64,
            bl + (size_t)l * 64, nullptr, nullptr, hn, N);
        float* tswap = hc; hc = hn; hn = tswap;
    }

    k_gemm<2><<<dim3(NB_P), dim3(256), 0, stream>>>(
        hc, nullptr, pair, W1, nullptr, b1, W2, b2, out, P);
}